// Round 1
// baseline (3273.978 us; speedup 1.0000x reference)
//
#include <hip/hip_runtime.h>
#include <math.h>

#define HID 51
#define TMAIN 1024
#define FUT 64
#define TT (TMAIN + FUT)

__device__ __forceinline__ float fast_sigmoid(float x) {
  return 1.0f / (1.0f + __expf(-x));
}
__device__ __forceinline__ float fast_tanh(float x) {
  // stable both directions: x>>0 -> 1, x<<0 -> -1
  return 1.0f - 2.0f / (__expf(2.0f * x) + 1.0f);
}

// acc[g] += sum_k w[g][k] * hbuf[k], k = 0..50. hbuf is 16B-aligned LDS.
// Per-lane weight set is only 2 gate rows (102 VGPRs) -> no spill.
__device__ __forceinline__ void dot2(const float* hbuf,
                                     const float (&w)[2][HID],
                                     float (&acc)[2]) {
  const float4* h4 = reinterpret_cast<const float4*>(hbuf);
#pragma unroll
  for (int q = 0; q < 12; ++q) {
    float4 hv = h4[q];
#pragma unroll
    for (int g = 0; g < 2; ++g) {
      acc[g] = fmaf(hv.x, w[g][4 * q + 0], acc[g]);
      acc[g] = fmaf(hv.y, w[g][4 * q + 1], acc[g]);
      acc[g] = fmaf(hv.z, w[g][4 * q + 2], acc[g]);
      acc[g] = fmaf(hv.w, w[g][4 * q + 3], acc[g]);
    }
  }
  float h48 = hbuf[48], h49 = hbuf[49], h50 = hbuf[50];
#pragma unroll
  for (int g = 0; g < 2; ++g) {
    acc[g] = fmaf(h48, w[g][48], acc[g]);
    acc[g] = fmaf(h49, w[g][49], acc[g]);
    acc[g] = fmaf(h50, w[g][50], acc[g]);
  }
}

// One block = one batch element. 6 waves, gate-pair split:
//   waves 0,1: Wh1 (L1) units [0,26)/[26,51); lane half 0 = gates {i,f},
//              lane half 1 = gates {g,o}; recombine via __shfl_xor(32).
//   waves 2,3: Wh2 partial (L2 recurrent) -> lds_p2
//   waves 4,5: Wi2 + p2 -> L2 cell -> h2, linear head
// Per-lane weights = 2 rows x 51 = 102 floats -> fits VGPRs (cap 170 via
// __launch_bounds__(384,3), keeps 2 blocks/CU resident).
__global__ __launch_bounds__(384, 3)
void lstm2_persistent(const float* __restrict__ input,
                      const float* __restrict__ Wi1,
                      const float* __restrict__ Wh1,
                      const float* __restrict__ bi1,
                      const float* __restrict__ bh1,
                      const float* __restrict__ Wi2,
                      const float* __restrict__ Wh2,
                      const float* __restrict__ bi2,
                      const float* __restrict__ bh2,
                      const float* __restrict__ Wlin,
                      const float* __restrict__ blin,
                      float* __restrict__ out) {
  __shared__ __align__(16) float lds_x[TMAIN];
  __shared__ __align__(16) float lds_h1[2][64];  // double-buffered (2 writer waves)
  __shared__ __align__(16) float lds_h2[64];
  __shared__ __align__(16) float lds_p2[4][64];
  __shared__ float lds_lin[2];

  const int b = blockIdx.x;
  const int tid = threadIdx.x;
  const int wid = tid >> 6;
  const int lane = tid & 63;
  const int half = lane >> 5;   // 0: gates {i,f}, 1: gates {g,o}
  const int l5 = lane & 31;
  const int base = (wid & 1) * 26;
  const int nu = (wid & 1) ? 25 : 26;
  const bool act = l5 < nu;
  const int u = base + (act ? l5 : 0);  // clamped unit index
  const int g0 = half * 2;

  // Stage this sequence's input row into LDS (coalesced).
  for (int i = tid; i < TMAIN; i += 384) lds_x[i] = input[b * TMAIN + i];
  if (tid < 64) {
    lds_h1[0][tid] = 0.0f;
    lds_h1[1][tid] = 0.0f;
    lds_h2[tid] = 0.0f;
  }

  // ---- Load this lane's 2 weight rows into registers ----
  float w[2][HID];
  float bias[2] = {0.f, 0.f};
  float wi1g[2] = {0.f, 0.f};
  float wlin_u = 0.0f;
  float c_state = 0.0f;

  const float* Wsel = (wid < 2) ? Wh1 : ((wid < 4) ? Wh2 : Wi2);
#pragma unroll
  for (int g = 0; g < 2; ++g) {
    const float* row = Wsel + ((g0 + g) * HID + u) * HID;
#pragma unroll
    for (int k = 0; k < HID; ++k) w[g][k] = row[k];
  }
  if (wid < 2) {
#pragma unroll
    for (int g = 0; g < 2; ++g) {
      bias[g] = bi1[(g0 + g) * HID + u] + bh1[(g0 + g) * HID + u];
      wi1g[g] = Wi1[(g0 + g) * HID + u];
    }
  } else if (wid >= 4) {
#pragma unroll
    for (int g = 0; g < 2; ++g)
      bias[g] = bi2[(g0 + g) * HID + u] + bh2[(g0 + g) * HID + u];
    wlin_u = Wlin[u];
  }
  const float blin_s = blin[0];

  __syncthreads();

  for (int t = 0; t <= TT; ++t) {
    const int pr = t & 1;  // h1 read buffer parity

    // ---- emit previous step's linear output; compute L1 input x ----
    float x = 0.0f;
    if (wid < 2) {
      float o_prev = 0.0f;
      if (t > 0) {
        o_prev = lds_lin[0] + lds_lin[1] + blin_s;  // written in phase 2 of t-1
        if (wid == 0 && lane == 63) out[b * TT + (t - 1)] = o_prev;
      }
      x = (t < TMAIN) ? lds_x[t] : o_prev;  // feedback in future phase
    }
    if (t == TT) break;  // final flush iteration: emit only

    // ---------------- phase 1 ----------------
    if (wid < 2) {
      // layer-1: acc = x*Wi1 + bias + Wh1 @ h1_prev (this half's 2 gates)
      float acc[2];
#pragma unroll
      for (int g = 0; g < 2; ++g) acc[g] = fmaf(x, wi1g[g], bias[g]);
      dot2(lds_h1[pr], w, acc);
      // recombine gate pairs across lane halves (both halves get all 4)
      float p0 = __shfl_xor(acc[0], 32);
      float p1 = __shfl_xor(acc[1], 32);
      float gi = half ? p0 : acc[0];
      float gf = half ? p1 : acc[1];
      float gg = half ? acc[0] : p0;
      float go = half ? acc[1] : p1;
      c_state = fast_sigmoid(gf) * c_state + fast_sigmoid(gi) * fast_tanh(gg);
      float h = fast_sigmoid(go) * fast_tanh(c_state);
      if (act && half == 0) lds_h1[pr ^ 1][u] = h;  // write NEW buffer (no race)
    } else if (wid < 4) {
      // layer-2 recurrent partial: Wh2 @ h2_prev (this half's 2 gates)
      float acc[2] = {0.f, 0.f};
      dot2(lds_h2, w, acc);
      if (act) {
        lds_p2[g0 + 0][u] = acc[0];
        lds_p2[g0 + 1][u] = acc[1];
      }
    }
    __syncthreads();  // h1_new + p2 visible

    // ---------------- phase 2 ----------------
    if (wid >= 4) {
      float acc[2];
      acc[0] = bias[0] + lds_p2[g0 + 0][u];
      acc[1] = bias[1] + lds_p2[g0 + 1][u];
      dot2(lds_h1[pr ^ 1], w, acc);  // Wi2 @ h1_new
      float p0 = __shfl_xor(acc[0], 32);
      float p1 = __shfl_xor(acc[1], 32);
      float gi = half ? p0 : acc[0];
      float gf = half ? p1 : acc[1];
      float gg = half ? acc[0] : p0;
      float go = half ? acc[1] : p1;
      c_state = fast_sigmoid(gf) * c_state + fast_sigmoid(gi) * fast_tanh(gg);
      float h = fast_sigmoid(go) * fast_tanh(c_state);
      float val = 0.0f;
      if (act && half == 0) {
        lds_h2[u] = h;
        val = wlin_u * h;
      }
      // linear head partial for this wave's units (butterfly over 64 lanes)
#pragma unroll
      for (int off = 32; off >= 1; off >>= 1) val += __shfl_xor(val, off);
      if (lane == 0) lds_lin[wid - 4] = val;  // combined + emitted next iter
    }
    __syncthreads();  // h2_new + lin partials visible for next timestep
  }
}

extern "C" void kernel_launch(void* const* d_in, const int* in_sizes, int n_in,
                              void* d_out, int out_size, void* d_ws,
                              size_t ws_size, hipStream_t stream) {
  const float* input = (const float*)d_in[0];
  const float* Wi1 = (const float*)d_in[1];
  const float* Wh1 = (const float*)d_in[2];
  const float* bi1 = (const float*)d_in[3];
  const float* bh1 = (const float*)d_in[4];
  const float* Wi2 = (const float*)d_in[5];
  const float* Wh2 = (const float*)d_in[6];
  const float* bi2 = (const float*)d_in[7];
  const float* bh2 = (const float*)d_in[8];
  const float* Wlin = (const float*)d_in[9];
  const float* blin = (const float*)d_in[10];
  float* out = (float*)d_out;

  const int B = in_sizes[0] / TMAIN;  // 512
  lstm2_persistent<<<B, 384, 0, stream>>>(input, Wi1, Wh1, bi1, bh1, Wi2, Wh2,
                                          bi2, bh2, Wlin, blin, out);
}

// Round 2
// 3256.276 us; speedup vs baseline: 1.0054x; 1.0054x over previous
//
#include <hip/hip_runtime.h>
#include <math.h>

#define HID 51
#define TMAIN 1024
#define FUT 64
#define TT (TMAIN + FUT)

__device__ __forceinline__ float fast_sigmoid(float x) {
  return 1.0f / (1.0f + __expf(-x));
}
__device__ __forceinline__ float fast_tanh(float x) {
  // stable both directions: x>>0 -> 1, x<<0 -> -1
  return 1.0f - 2.0f / (__expf(2.0f * x) + 1.0f);
}

// acc[g] += sum_k w[g][k] * hbuf[k], k = 0..50. hbuf is 16B-aligned LDS.
__device__ __forceinline__ void dot2(const float* hbuf,
                                     const float (&w)[2][HID],
                                     float (&acc)[2]) {
  const float4* h4 = reinterpret_cast<const float4*>(hbuf);
#pragma unroll
  for (int q = 0; q < 12; ++q) {
    float4 hv = h4[q];
#pragma unroll
    for (int g = 0; g < 2; ++g) {
      acc[g] = fmaf(hv.x, w[g][4 * q + 0], acc[g]);
      acc[g] = fmaf(hv.y, w[g][4 * q + 1], acc[g]);
      acc[g] = fmaf(hv.z, w[g][4 * q + 2], acc[g]);
      acc[g] = fmaf(hv.w, w[g][4 * q + 3], acc[g]);
    }
  }
  float h48 = hbuf[48], h49 = hbuf[49], h50 = hbuf[50];
#pragma unroll
  for (int g = 0; g < 2; ++g) {
    acc[g] = fmaf(h48, w[g][48], acc[g]);
    acc[g] = fmaf(h49, w[g][49], acc[g]);
    acc[g] = fmaf(h50, w[g][50], acc[g]);
  }
}

// One block = one batch element. 6 waves, gate-pair split:
//   waves 0,1: Wh1 (L1) units [0,26)/[26,51); lane half 0 = gates {i,f},
//              lane half 1 = gates {g,o}; recombine via __shfl_xor(32).
//   waves 2,3: Wh2 partial (L2 recurrent) -> lds_p2
//   waves 4,5: Wi2 + p2 -> L2 cell -> h2, linear head
// Per-lane weights = 2 rows x 51 = 102 floats. R1 lesson: without the asm
// pin below, LLVM remats the invariant weight loads INSIDE the t-loop
// (VGPR_Count=68 with 102 live floats, no scratch) -> L1-BW-bound at
// ~156 KB/step/block. The pin makes the asm the defining instruction, so
// the values must stay in VGPRs. 102 + ~45 working fits the 170-reg cap
// of __launch_bounds__(384,3) (3 waves/SIMD, 2 blocks/CU resident).
__global__ __launch_bounds__(384, 3)
void lstm2_persistent(const float* __restrict__ input,
                      const float* __restrict__ Wi1,
                      const float* __restrict__ Wh1,
                      const float* __restrict__ bi1,
                      const float* __restrict__ bh1,
                      const float* __restrict__ Wi2,
                      const float* __restrict__ Wh2,
                      const float* __restrict__ bi2,
                      const float* __restrict__ bh2,
                      const float* __restrict__ Wlin,
                      const float* __restrict__ blin,
                      float* __restrict__ out) {
  __shared__ __align__(16) float lds_x[TMAIN];
  __shared__ __align__(16) float lds_h1[2][64];  // double-buffered
  __shared__ __align__(16) float lds_h2[64];
  __shared__ __align__(16) float lds_p2[4][64];
  __shared__ float lds_lin[2];

  const int b = blockIdx.x;
  const int tid = threadIdx.x;
  const int wid = tid >> 6;
  const int lane = tid & 63;
  const int half = lane >> 5;   // 0: gates {i,f}, 1: gates {g,o}
  const int l5 = lane & 31;
  const int base = (wid & 1) * 26;
  const int nu = (wid & 1) ? 25 : 26;
  const bool act = l5 < nu;
  const int u = base + (act ? l5 : 0);  // clamped unit index
  const int g0 = half * 2;

  // Stage this sequence's input row into LDS (coalesced).
  for (int i = tid; i < TMAIN; i += 384) lds_x[i] = input[b * TMAIN + i];
  if (tid < 64) {
    lds_h1[0][tid] = 0.0f;
    lds_h1[1][tid] = 0.0f;
    lds_h2[tid] = 0.0f;
  }

  // ---- Load this lane's 2 weight rows into registers ----
  float w[2][HID];
  float bias[2] = {0.f, 0.f};
  float wi1g[2] = {0.f, 0.f};
  float wlin_u = 0.0f;
  float c_state = 0.0f;

  const float* Wsel = (wid < 2) ? Wh1 : ((wid < 4) ? Wh2 : Wi2);
#pragma unroll
  for (int g = 0; g < 2; ++g) {
    const float* row = Wsel + ((g0 + g) * HID + u) * HID;
#pragma unroll
    for (int k = 0; k < HID; ++k) w[g][k] = row[k];
  }
  if (wid < 2) {
#pragma unroll
    for (int g = 0; g < 2; ++g) {
      bias[g] = bi1[(g0 + g) * HID + u] + bh1[(g0 + g) * HID + u];
      wi1g[g] = Wi1[(g0 + g) * HID + u];
    }
  } else if (wid >= 4) {
#pragma unroll
    for (int g = 0; g < 2; ++g)
      bias[g] = bi2[(g0 + g) * HID + u] + bh2[(g0 + g) * HID + u];
    wlin_u = Wlin[u];
  }
  const float blin_s = blin[0];

  // ---- PIN: make each weight's defining instruction an opaque asm so the
  // compiler cannot rematerialize the global loads inside the t-loop.
#pragma unroll
  for (int g = 0; g < 2; ++g) {
#pragma unroll
    for (int k = 0; k < HID; ++k) asm volatile("" : "+v"(w[g][k]));
    asm volatile("" : "+v"(bias[g]), "+v"(wi1g[g]));
  }
  asm volatile("" : "+v"(wlin_u));

  __syncthreads();

  for (int t = 0; t <= TT; ++t) {
    const int pr = t & 1;  // h1 read buffer parity

    // ---- emit previous step's linear output; compute L1 input x ----
    float x = 0.0f;
    if (wid < 2) {
      float o_prev = 0.0f;
      if (t > 0) {
        o_prev = lds_lin[0] + lds_lin[1] + blin_s;  // from phase 2 of t-1
        if (wid == 0 && lane == 63) out[b * TT + (t - 1)] = o_prev;
      }
      x = (t < TMAIN) ? lds_x[t] : o_prev;  // feedback in future phase
    }
    if (t == TT) break;  // final flush iteration: emit only

    // ---------------- phase 1 ----------------
    if (wid < 2) {
      // layer-1: acc = x*Wi1 + bias + Wh1 @ h1_prev (this half's 2 gates)
      float acc[2];
#pragma unroll
      for (int g = 0; g < 2; ++g) acc[g] = fmaf(x, wi1g[g], bias[g]);
      dot2(lds_h1[pr], w, acc);
      // recombine gate pairs across lane halves (both halves get all 4)
      float p0 = __shfl_xor(acc[0], 32);
      float p1 = __shfl_xor(acc[1], 32);
      float gi = half ? p0 : acc[0];
      float gf = half ? p1 : acc[1];
      float gg = half ? acc[0] : p0;
      float go = half ? acc[1] : p1;
      c_state = fast_sigmoid(gf) * c_state + fast_sigmoid(gi) * fast_tanh(gg);
      float h = fast_sigmoid(go) * fast_tanh(c_state);
      if (act && half == 0) lds_h1[pr ^ 1][u] = h;  // write NEW buffer
    } else if (wid < 4) {
      // layer-2 recurrent partial: Wh2 @ h2_prev (this half's 2 gates)
      float acc[2] = {0.f, 0.f};
      dot2(lds_h2, w, acc);
      if (act) {
        lds_p2[g0 + 0][u] = acc[0];
        lds_p2[g0 + 1][u] = acc[1];
      }
    }
    __syncthreads();  // h1_new + p2 visible

    // ---------------- phase 2 ----------------
    if (wid >= 4) {
      float acc[2];
      acc[0] = bias[0] + lds_p2[g0 + 0][u];
      acc[1] = bias[1] + lds_p2[g0 + 1][u];
      dot2(lds_h1[pr ^ 1], w, acc);  // Wi2 @ h1_new
      float p0 = __shfl_xor(acc[0], 32);
      float p1 = __shfl_xor(acc[1], 32);
      float gi = half ? p0 : acc[0];
      float gf = half ? p1 : acc[1];
      float gg = half ? acc[0] : p0;
      float go = half ? acc[1] : p1;
      c_state = fast_sigmoid(gf) * c_state + fast_sigmoid(gi) * fast_tanh(gg);
      float h = fast_sigmoid(go) * fast_tanh(c_state);
      float val = 0.0f;
      if (act && half == 0) {
        lds_h2[u] = h;
        val = wlin_u * h;
      }
      // linear head partial for this wave's units (butterfly over 64 lanes)
#pragma unroll
      for (int off = 32; off >= 1; off >>= 1) val += __shfl_xor(val, off);
      if (lane == 0) lds_lin[wid - 4] = val;  // combined + emitted next iter
    }
    __syncthreads();  // h2_new + lin partials visible for next timestep
  }
}

extern "C" void kernel_launch(void* const* d_in, const int* in_sizes, int n_in,
                              void* d_out, int out_size, void* d_ws,
                              size_t ws_size, hipStream_t stream) {
  const float* input = (const float*)d_in[0];
  const float* Wi1 = (const float*)d_in[1];
  const float* Wh1 = (const float*)d_in[2];
  const float* bi1 = (const float*)d_in[3];
  const float* bh1 = (const float*)d_in[4];
  const float* Wi2 = (const float*)d_in[5];
  const float* Wh2 = (const float*)d_in[6];
  const float* bi2 = (const float*)d_in[7];
  const float* bh2 = (const float*)d_in[8];
  const float* Wlin = (const float*)d_in[9];
  const float* blin = (const float*)d_in[10];
  float* out = (float*)d_out;

  const int B = in_sizes[0] / TMAIN;  // 512
  lstm2_persistent<<<B, 384, 0, stream>>>(input, Wi1, Wh1, bi1, bh1, Wi2, Wh2,
                                          bi2, bh2, Wlin, blin, out);
}